// Round 7
// baseline (125.530 us; speedup 1.0000x reference)
//
#include <hip/hip_runtime.h>
#include <hip/hip_bf16.h>
#include <stdint.h>

#define FEAT 1024
#define NALL 1000
#define NCLS 100
#define NEP 1024      // epb rows: 4 tiles x (25 classes x 10 protos + 6 pad)

typedef __attribute__((ext_vector_type(8))) short short8;
typedef __attribute__((ext_vector_type(4))) float f32x4;
typedef __attribute__((ext_vector_type(4))) unsigned short us4;

__device__ __forceinline__ unsigned short f2bf(float f) {
    union { float f; uint32_t u; } v; v.f = f;
    uint32_t u = v.u;
    return (unsigned short)((u + 0x7FFFu + ((u >> 16) & 1u)) >> 16);
}

__device__ __forceinline__ void gload16(const void* g, void* l) {
    __builtin_amdgcn_global_load_lds((__attribute__((address_space(1))) void*)g,
                                     (__attribute__((address_space(3))) void*)l,
                                     16, 0, 0);
}

// K1: x (16384x1024 f32) -> bf16, plus row sum-of-squares
__global__ __launch_bounds__(256) void k_prep_x(const float* __restrict__ x,
                                                unsigned short* __restrict__ xb,
                                                float* __restrict__ xsq) {
    int row = blockIdx.x * 4 + (threadIdx.x >> 6);
    int lane = threadIdx.x & 63;
    const float4* xr = (const float4*)(x + (size_t)row * FEAT);
    float s = 0.f;
#pragma unroll
    for (int i = 0; i < 4; ++i) {
        float4 v = xr[lane + i * 64];
        s += v.x * v.x + v.y * v.y + v.z * v.z + v.w * v.w;
        us4 o;
        o[0] = f2bf(v.x); o[1] = f2bf(v.y); o[2] = f2bf(v.z); o[3] = f2bf(v.w);
        *(us4*)(xb + (size_t)row * FEAT + (size_t)(lane + i * 64) * 4) = o;
    }
#pragma unroll
    for (int off = 32; off; off >>= 1) s += __shfl_xor(s, off);
    if (lane == 0) xsq[row] = s;
}

// K2a: protos (1000x1024 f32) -> bf16 padded to 1024 rows (pad = 0)
__global__ __launch_bounds__(256) void k_prep_protos(const float* __restrict__ p,
                                                     unsigned short* __restrict__ pb) {
    int row = blockIdx.x;
    int t = threadIdx.x;
    us4 o;
    if (row < NALL) {
        float4 v = ((const float4*)(p + (size_t)row * FEAT))[t];
        o[0] = f2bf(v.x); o[1] = f2bf(v.y); o[2] = f2bf(v.z); o[3] = f2bf(v.w);
    } else {
        o[0] = 0; o[1] = 0; o[2] = 0; o[3] = 0;
    }
    *(us4*)(pb + (size_t)row * FEAT + (size_t)t * 4) = o;
}

// K2b: enc_w (1024x1024 f32) -> transposed bf16 (wt[n][k] = enc_w[k][n])
__global__ __launch_bounds__(256) void k_transpose_w(const float* __restrict__ w,
                                                     unsigned short* __restrict__ wt) {
    __shared__ float tile[32][33];
    int bx = blockIdx.x, by = blockIdx.y;
    int tx = threadIdx.x & 31, ty = threadIdx.x >> 5;
#pragma unroll
    for (int i = 0; i < 4; ++i) {
        int r = by * 32 + ty + i * 8;
        tile[ty + i * 8][tx] = w[(size_t)r * FEAT + bx * 32 + tx];
    }
    __syncthreads();
#pragma unroll
    for (int i = 0; i < 4; ++i) {
        int r = bx * 32 + ty + i * 8;
        wt[(size_t)r * FEAT + by * 32 + tx] = f2bf(tile[tx][ty + i * 8]);
    }
}

// K2c: encoder GEMM: ep = protos @ enc_w + b. Proto row n (proto p=n/100,
// class c=n%100) -> epb row 256*(c/25) + (c%25)*10 + p  (25 classes/tile).
__global__ __launch_bounds__(256) void k_enc_gemm(const unsigned short* __restrict__ A,
                                                  const unsigned short* __restrict__ B,
                                                  const float* __restrict__ bias,
                                                  unsigned short* __restrict__ epb) {
    __shared__ __align__(16) char smem[32768];
    int bm0 = (blockIdx.x >> 3) * 128;
    int bn0 = (blockIdx.x & 7) * 128;
    int tid = threadIdx.x, lane = tid & 63, wid = tid >> 6;
    int wm = wid >> 1, wn = wid & 1;
    int ls = lane >> 4, lf = lane & 15;
    f32x4 acc[4][4] = {};
    for (int k0 = 0; k0 < FEAT; k0 += 64) {
        __syncthreads();
#pragma unroll
        for (int i = 0; i < 4; ++i) {
            int ci = wid + i * 4;
            int r = ci * 8 + (lane >> 3), c = (lane & 7) * 8;
            gload16(A + (size_t)(bm0 + r) * FEAT + k0 + c, smem + ci * 1024);
            gload16(B + (size_t)(bn0 + r) * FEAT + k0 + c, smem + 16384 + ci * 1024);
        }
        __syncthreads();
#pragma unroll
        for (int kk = 0; kk < 64; kk += 32) {
            short8 a[4], b[4];
#pragma unroll
            for (int f = 0; f < 4; ++f) {
                a[f] = *(const short8*)(smem + (wm * 64 + f * 16 + lf) * 128 + (kk + ls * 8) * 2);
                b[f] = *(const short8*)(smem + 16384 + (wn * 64 + f * 16 + lf) * 128 + (kk + ls * 8) * 2);
            }
#pragma unroll
            for (int fm = 0; fm < 4; ++fm)
#pragma unroll
                for (int fn = 0; fn < 4; ++fn)
                    acc[fm][fn] = __builtin_amdgcn_mfma_f32_16x16x32_bf16(a[fm], b[fn], acc[fm][fn], 0, 0, 0);
        }
    }
    int tr = ls * 4, tc = lf;
#pragma unroll
    for (int fn = 0; fn < 4; ++fn) {
        int col = bn0 + wn * 64 + fn * 16 + tc;
        float bb = bias[col];
#pragma unroll
        for (int fm = 0; fm < 4; ++fm) {
#pragma unroll
            for (int r = 0; r < 4; ++r) {
                int row = bm0 + wm * 64 + fm * 16 + tr + r;
                if (row < NALL) {
                    int c = row % 100, pp = row / 100;
                    int pr = 256 * (c / 25) + (c % 25) * 10 + pp;
                    epb[(size_t)pr * FEAT + col] = f2bf(acc[fm][fn][r] + bb);
                }
            }
        }
    }
}

// K2d: p_sq per epb row; pad rows (row%256 >= 250) get 1e30
__global__ __launch_bounds__(256) void k_psq(const unsigned short* __restrict__ epb,
                                             float* __restrict__ psq) {
    int row = blockIdx.x * 4 + (threadIdx.x >> 6);
    int lane = threadIdx.x & 63;
    if (row >= NEP) return;
    float s = 0.f;
    const short8* r8 = (const short8*)(epb + (size_t)row * FEAT);
#pragma unroll
    for (int i = 0; i < 2; ++i) {
        short8 v = r8[lane + i * 64];
#pragma unroll
        for (int j = 0; j < 8; ++j) {
            union { uint32_t u; float f; } c;
            c.u = ((uint32_t)(unsigned short)v[j]) << 16;
            s += c.f * c.f;
        }
    }
#pragma unroll
    for (int off = 32; off; off >>= 1) s += __shfl_xor(s, off);
    if (lane == 0) psq[row] = ((row & 255) < 250) ? s : 1e30f;
}

#define WAITV(n) asm volatile("s_waitcnt vmcnt(" #n ")")
#define SB0() __builtin_amdgcn_sched_barrier(0)

// K3: 256x256x64 tiled GEMM (m201-style schedule) + fused sqrt/min epilogue.
// 8 waves (2M x 4N), wave-tile 128x64, acc[8][4] f32x4 = 128 VGPR.
// LDS ring: 2 bufs x 64 KB; buf = {A0,A1,B0,B1} half-tiles of 128x64 bf16 (16 KB).
// Per K-tile: stage h0(next) -> vmcnt(2) [counted! never 0 mid-loop] ->
// s_barrier -> 4 phases {ds_read | stage next half | setprio+16 MFMA} -> s_barrier.
// Grid = 64 M x 4 N = 256 blocks exactly (1/CU, zero tail).
__global__ __launch_bounds__(512, 1) void k_main(const unsigned short* __restrict__ xb,
                                                 const unsigned short* __restrict__ epb,
                                                 const float* __restrict__ xsq,
                                                 const float* __restrict__ psq,
                                                 float* __restrict__ out) {
    __shared__ __align__(16) char smem[133120];   // 128 KB ring + xsq_s + psq_s
    const int bid = blockIdx.x;                   // 256
    const int idx = (bid & 7) * 32 + (bid >> 3);  // XCD-chunked
    const int mt = idx >> 2, nt = idx & 3;
    const int bm0 = mt * 256;
    const int bn0 = nt * 256;
    const int tid = threadIdx.x, lane = tid & 63, wid = tid >> 6;
    const int wm = wid >> 2, wn = wid & 3;        // 2M x 4N
    const int ls = lane >> 4, lf = lane & 15;
    float* xsq_s = (float*)(smem + 131072);
    float* psq_s = (float*)(smem + 132096);
    if (tid < 256) xsq_s[tid] = xsq[bm0 + tid];
    else psq_s[tid - 256] = psq[bn0 + tid - 256];

    // ---- staging (rule 21): linear LDS dest, inverse-swizzled global col ----
    // half-tile 16 KB = 128 rows x 64 B; thread tid, load i: row = 64*i + tid>>3,
    // dest slot = tid&7; source logical k-slot = (tid&7) ^ (row&7).
    const int r0 = tid >> 3;
    const int scol = (((tid & 7) ^ (r0 & 7)) << 3);
    const unsigned short* sA0 = xb  + (size_t)(bm0 + r0) * FEAT + scol;
    const unsigned short* sA1 = xb  + (size_t)(bm0 + 128 + r0) * FEAT + scol;
    const unsigned short* sB0 = epb + (size_t)(bn0 + r0) * FEAT + scol;
    const unsigned short* sB1 = epb + (size_t)(bn0 + 128 + r0) * FEAT + scol;
    const int ldst = tid * 16;

#define STG(SP, CB, HH, KT) do {                                               \
    gload16((SP) + (KT) * 64,         smem + (CB) * 65536 + (HH) * 16384 + ldst); \
    gload16((SP) + (KT) * 64 + 65536, smem + (CB) * 65536 + (HH) * 16384 + 8192 + ldst); \
} while (0)

    // ---- swizzled ds_read addresses ----
    const int swb = lf & 7;
    int so[2] = { ((0 + ls) ^ swb) << 4, ((4 + ls) ^ swb) << 4 };
    int raA[4], raB[4];
#pragma unroll
    for (int f = 0; f < 4; ++f) raA[f] = wm * 16384 + (16 * f + lf) * 128;
#pragma unroll
    for (int f = 0; f < 4; ++f)
        raB[f] = 32768 + (wn >> 1) * 16384 + (64 * (wn & 1) + 16 * f + lf) * 128;

    short8 a[4][2], b[2][2];
    f32x4 acc[8][4] = {};

#define DSA(FMH) do {                                                          \
    _Pragma("unroll") for (int f_ = 0; f_ < 4; ++f_)                           \
    _Pragma("unroll") for (int k_ = 0; k_ < 2; ++k_)                           \
        a[f_][k_] = *(const short8*)(base + (FMH) * 8192 + raA[f_] + so[k_]);  \
} while (0)
#define DSB(FNH) do {                                                          \
    _Pragma("unroll") for (int g_ = 0; g_ < 2; ++g_)                           \
    _Pragma("unroll") for (int k_ = 0; k_ < 2; ++k_)                           \
        b[g_][k_] = *(const short8*)(base + raB[(FNH) * 2 + g_] + so[k_]);     \
} while (0)
#define MM(FMH, FNH) do {                                                      \
    _Pragma("unroll") for (int f_ = 0; f_ < 4; ++f_)                           \
    _Pragma("unroll") for (int g_ = 0; g_ < 2; ++g_)                           \
    _Pragma("unroll") for (int k_ = 0; k_ < 2; ++k_)                           \
        acc[(FMH) * 4 + f_][(FNH) * 2 + g_] = __builtin_amdgcn_mfma_f32_16x16x32_bf16( \
            a[f_][k_], b[g_][k_], acc[(FMH) * 4 + f_][(FNH) * 2 + g_], 0, 0, 0); \
} while (0)

#define TILE(KT, CUR, PRE) do {                                                \
    if (PRE) STG(sA0, (CUR) ^ 1, 0, (KT) + 1);                                 \
    SB0();                                                                     \
    if (PRE) { WAITV(2); } else { WAITV(0); }                                  \
    SB0();                                                                     \
    __builtin_amdgcn_s_barrier();                                              \
    SB0();                                                                     \
    const char* base = (const char*)smem + (CUR) * 65536;                      \
    DSA(0); DSB(0);                                                            \
    __builtin_amdgcn_s_setprio(1); MM(0, 0); __builtin_amdgcn_s_setprio(0);    \
    SB0();                                                                     \
    if (PRE) STG(sA1, (CUR) ^ 1, 1, (KT) + 1);                                 \
    DSB(1);                                                                    \
    __builtin_amdgcn_s_setprio(1); MM(0, 1); __builtin_amdgcn_s_setprio(0);    \
    SB0();                                                                     \
    if (PRE) STG(sB0, (CUR) ^ 1, 2, (KT) + 1);                                 \
    DSA(1); DSB(0);                                                            \
    __builtin_amdgcn_s_setprio(1); MM(1, 0); __builtin_amdgcn_s_setprio(0);    \
    SB0();                                                                     \
    if (PRE) STG(sB1, (CUR) ^ 1, 3, (KT) + 1);                                 \
    DSB(1);                                                                    \
    __builtin_amdgcn_s_setprio(1); MM(1, 1); __builtin_amdgcn_s_setprio(0);    \
    SB0();                                                                     \
    __builtin_amdgcn_s_barrier();                                              \
} while (0)

    // prologue: stage tile 0 fully into buf 0
    STG(sA0, 0, 0, 0); STG(sA1, 0, 1, 0); STG(sB0, 0, 2, 0); STG(sB1, 0, 3, 0);

    int kt = 0;
    for (int k2 = 0; k2 < 7; ++k2) {
        TILE(kt, 0, 1); ++kt;
        TILE(kt, 1, 1); ++kt;
    }
    TILE(kt, 0, 1); ++kt;
    TILE(kt, 1, 0);   // kt = 15: no prefetch, drain

#undef TILE
#undef STG

    // ---- epilogue: d = sqrt(max(xsq - 2*dot + psq, 0)); min over 10 protos ----
    // 4 passes over row-quarters (64 rows); dls[64][257] f32 (65.8 KB, reuses ring)
    float* dls = (float*)smem;
#pragma unroll
    for (int p = 0; p < 4; ++p) {
        __syncthreads();
        if (wm == (p >> 1)) {
            const int fmB = 4 * (p & 1);
#pragma unroll
            for (int ff = 0; ff < 4; ++ff) {
#pragma unroll
                for (int fn = 0; fn < 4; ++fn) {
                    int col = 64 * wn + 16 * fn + lf;
                    float pq = psq_s[col];
#pragma unroll
                    for (int r = 0; r < 4; ++r) {
                        int lr = 16 * ff + 4 * ls + r;
                        float d2 = xsq_s[64 * p + lr] - 2.f * acc[fmB + ff][fn][r] + pq;
                        dls[lr * 257 + col] = sqrtf(fmaxf(d2, 0.f));
                    }
                }
            }
        }
        __syncthreads();
#pragma unroll
        for (int i = 0; i < 4; ++i) {
            int task = tid + i * 512;          // 1600 tasks: 64 rows x 25 classes
            if (task < 1600) {
                int rr = task / 25, cl = task % 25;
                float m = 1e30f;
#pragma unroll
                for (int j = 0; j < 10; ++j) m = fminf(m, dls[rr * 257 + cl * 10 + j]);
                out[(size_t)(bm0 + 64 * p + rr) * NCLS + nt * 25 + cl] = m;
            }
        }
    }
}

extern "C" void kernel_launch(void* const* d_in, const int* in_sizes, int n_in,
                              void* d_out, int out_size, void* d_ws, size_t ws_size,
                              hipStream_t stream) {
    const float* x      = (const float*)d_in[0];
    const float* protos = (const float*)d_in[1];
    const float* enc_w  = (const float*)d_in[2];
    const float* enc_b  = (const float*)d_in[3];
    float* out = (float*)d_out;
    char* ws = (char*)d_ws;

    unsigned short* xb  = (unsigned short*)ws;                   // 16384*1024*2 = 33554432
    unsigned short* epb = (unsigned short*)(ws + 33554432);      // 1024*1024*2  = 2097152
    unsigned short* prb = (unsigned short*)(ws + 35651584);      // 1024*1024*2  = 2097152
    unsigned short* wtb = (unsigned short*)(ws + 37748736);      // 1024*1024*2  = 2097152
    float* xsq = (float*)(ws + 39845888);                        // 16384*4
    float* psq = (float*)(ws + 39911424);                        // 1024*4

    // zero whole epb so pad rows are defined
    hipMemsetAsync(epb, 0, (size_t)NEP * FEAT * 2, stream);

    k_prep_x<<<4096, 256, 0, stream>>>(x, xb, xsq);
    k_prep_protos<<<1024, 256, 0, stream>>>(protos, prb);
    k_transpose_w<<<dim3(32, 32), 256, 0, stream>>>(enc_w, wtb);
    k_enc_gemm<<<64, 256, 0, stream>>>(prb, wtb, enc_b, epb);
    k_psq<<<256, 256, 0, stream>>>(epb, psq);
    k_main<<<256, 512, 0, stream>>>(xb, epb, xsq, psq, out);
}

// Round 9
// 119.404 us; speedup vs baseline: 1.0513x; 1.0513x over previous
//
#include <hip/hip_runtime.h>
#include <hip/hip_bf16.h>
#include <stdint.h>

#define FEAT 1024
#define NALL 1000
#define NPAD 1120
#define NCLS 100

typedef __attribute__((ext_vector_type(8))) short short8;
typedef __attribute__((ext_vector_type(4))) float f32x4;
typedef __attribute__((ext_vector_type(4))) unsigned short us4;

__device__ __forceinline__ unsigned short f2bf(float f) {
    union { float f; uint32_t u; } v; v.f = f;
    uint32_t u = v.u;
    return (unsigned short)((u + 0x7FFFu + ((u >> 16) & 1u)) >> 16);
}

__device__ __forceinline__ void gload16(const void* g, void* l) {
    __builtin_amdgcn_global_load_lds((__attribute__((address_space(1))) void*)g,
                                     (__attribute__((address_space(3))) void*)l,
                                     16, 0, 0);
}

// K1: x (16384x1024 f32) -> bf16, plus row sum-of-squares
__global__ __launch_bounds__(256) void k_prep_x(const float* __restrict__ x,
                                                unsigned short* __restrict__ xb,
                                                float* __restrict__ xsq) {
    int row = blockIdx.x * 4 + (threadIdx.x >> 6);
    int lane = threadIdx.x & 63;
    const float4* xr = (const float4*)(x + (size_t)row * FEAT);
    float s = 0.f;
#pragma unroll
    for (int i = 0; i < 4; ++i) {
        float4 v = xr[lane + i * 64];
        s += v.x * v.x + v.y * v.y + v.z * v.z + v.w * v.w;
        us4 o;
        o[0] = f2bf(v.x); o[1] = f2bf(v.y); o[2] = f2bf(v.z); o[3] = f2bf(v.w);
        *(us4*)(xb + (size_t)row * FEAT + (size_t)(lane + i * 64) * 4) = o;
    }
#pragma unroll
    for (int off = 32; off; off >>= 1) s += __shfl_xor(s, off);
    if (lane == 0) xsq[row] = s;
}

// K2a: protos (1000x1024 f32) -> bf16 padded to 1024 rows (pad = 0)
__global__ __launch_bounds__(256) void k_prep_protos(const float* __restrict__ p,
                                                     unsigned short* __restrict__ pb) {
    int row = blockIdx.x;
    int t = threadIdx.x;
    us4 o;
    if (row < NALL) {
        float4 v = ((const float4*)(p + (size_t)row * FEAT))[t];
        o[0] = f2bf(v.x); o[1] = f2bf(v.y); o[2] = f2bf(v.z); o[3] = f2bf(v.w);
    } else {
        o[0] = 0; o[1] = 0; o[2] = 0; o[3] = 0;
    }
    *(us4*)(pb + (size_t)row * FEAT + (size_t)t * 4) = o;
}

// K2b: enc_w (1024x1024 f32) -> transposed bf16 (wt[n][k] = enc_w[k][n])
__global__ __launch_bounds__(256) void k_transpose_w(const float* __restrict__ w,
                                                     unsigned short* __restrict__ wt) {
    __shared__ float tile[32][33];
    int bx = blockIdx.x, by = blockIdx.y;
    int tx = threadIdx.x & 31, ty = threadIdx.x >> 5;
#pragma unroll
    for (int i = 0; i < 4; ++i) {
        int r = by * 32 + ty + i * 8;
        tile[ty + i * 8][tx] = w[(size_t)r * FEAT + bx * 32 + tx];
    }
    __syncthreads();
#pragma unroll
    for (int i = 0; i < 4; ++i) {
        int r = bx * 32 + ty + i * 8;
        wt[(size_t)r * FEAT + by * 32 + tx] = f2bf(tile[tx][ty + i * 8]);
    }
}

// K2c: encoder GEMM: ep = protos @ enc_w + b. Writes epb rows in class-major
// permuted order: n' = (n%100)*10 + n/100.
__global__ __launch_bounds__(256) void k_enc_gemm(const unsigned short* __restrict__ A,
                                                  const unsigned short* __restrict__ B,
                                                  const float* __restrict__ bias,
                                                  unsigned short* __restrict__ epb) {
    __shared__ __align__(16) char smem[32768];
    int bm0 = (blockIdx.x >> 3) * 128;
    int bn0 = (blockIdx.x & 7) * 128;
    int tid = threadIdx.x, lane = tid & 63, wid = tid >> 6;
    int wm = wid >> 1, wn = wid & 1;
    int ls = lane >> 4, lf = lane & 15;
    f32x4 acc[4][4] = {};
    for (int k0 = 0; k0 < FEAT; k0 += 64) {
        __syncthreads();
#pragma unroll
        for (int i = 0; i < 4; ++i) {
            int ci = wid + i * 4;
            int r = ci * 8 + (lane >> 3), c = (lane & 7) * 8;
            gload16(A + (size_t)(bm0 + r) * FEAT + k0 + c, smem + ci * 1024);
            gload16(B + (size_t)(bn0 + r) * FEAT + k0 + c, smem + 16384 + ci * 1024);
        }
        __syncthreads();
#pragma unroll
        for (int kk = 0; kk < 64; kk += 32) {
            short8 a[4], b[4];
#pragma unroll
            for (int f = 0; f < 4; ++f) {
                a[f] = *(const short8*)(smem + (wm * 64 + f * 16 + lf) * 128 + (kk + ls * 8) * 2);
                b[f] = *(const short8*)(smem + 16384 + (wn * 64 + f * 16 + lf) * 128 + (kk + ls * 8) * 2);
            }
#pragma unroll
            for (int fm = 0; fm < 4; ++fm)
#pragma unroll
                for (int fn = 0; fn < 4; ++fn)
                    acc[fm][fn] = __builtin_amdgcn_mfma_f32_16x16x32_bf16(a[fm], b[fn], acc[fm][fn], 0, 0, 0);
        }
    }
    int tr = ls * 4, tc = lf;
#pragma unroll
    for (int fn = 0; fn < 4; ++fn) {
        int col = bn0 + wn * 64 + fn * 16 + tc;
        float bb = bias[col];
#pragma unroll
        for (int fm = 0; fm < 4; ++fm) {
#pragma unroll
            for (int r = 0; r < 4; ++r) {
                int row = bm0 + wm * 64 + fm * 16 + tr + r;
                if (row < NALL) {
                    int pr = (row % 100) * 10 + row / 100;
                    epb[(size_t)pr * FEAT + col] = f2bf(acc[fm][fn][r] + bb);
                }
            }
        }
    }
}

// K2d: p_sq per (permuted) ep row; pad rows get 1e30
__global__ __launch_bounds__(256) void k_psq(const unsigned short* __restrict__ epb,
                                             float* __restrict__ psq) {
    int row = blockIdx.x * 4 + (threadIdx.x >> 6);
    int lane = threadIdx.x & 63;
    if (row >= NPAD) return;
    float s = 0.f;
    const short8* r8 = (const short8*)(epb + (size_t)row * FEAT);
#pragma unroll
    for (int i = 0; i < 2; ++i) {
        short8 v = r8[lane + i * 64];
#pragma unroll
        for (int j = 0; j < 8; ++j) {
            union { uint32_t u; float f; } c;
            c.u = ((uint32_t)(unsigned short)v[j]) << 16;
            s += c.f * c.f;
        }
    }
#pragma unroll
    for (int off = 32; off; off >>= 1) s += __shfl_xor(s, off);
    if (lane == 0) psq[row] = (row < NALL) ? s : 1e30f;
}

// K3: main GEMM (16384 x 1120 x 1024) + fused sqrt + min-over-10-protos epilogue.
// BM=128, BN=160, BK=64, 4 waves (2x2), frags 4x5. SINGLE-buffered LDS (38 KB)
// + plain 2-barrier __syncthreads loop (r1-proven) + T2 swizzle (r2-proven).
// Goal: 4 blocks/CU (16 waves/CU) — TLP is the only lever that has moved perf
// (2-block/CU rounds: 94-104 us; 1-block/CU rounds: 107-152 us). No asm.
__global__ __launch_bounds__(256) void k_main(const unsigned short* __restrict__ xb,
                                              const unsigned short* __restrict__ epb,
                                              const float* __restrict__ xsq,
                                              const float* __restrict__ psq,
                                              float* __restrict__ out) {
    __shared__ __align__(16) char smem[38016];
    // A tile [128][64] at +0 (16 KB), B tile [160][64] at +16384 (20 KB),
    // xsq_s at +36864 (512 B), psq_s at +37376 (640 B). Total 38016 -> 4 blocks/CU.
    const int bid = blockIdx.x;                       // 896 blocks
    const int swz = (bid & 7) * 112 + (bid >> 3);     // XCD-chunk swizzle (896 % 8 == 0)
    const int bm0 = (swz / 7) * 128;
    const int bn0 = (swz % 7) * 160;
    const int tid = threadIdx.x, lane = tid & 63, wid = tid >> 6;
    const int wm = wid >> 1, wn = wid & 1;
    const int ls = lane >> 4, lf = lane & 15;
    float* xsq_s = (float*)(smem + 36864);
    float* psq_s = (float*)(smem + 37376);
    if (tid < 128) xsq_s[tid] = xsq[bm0 + tid];
    if (tid < 160) psq_s[tid] = psq[bn0 + tid];

    // staging source pointers: lane (r=lane>>3, cb=lane&7) loads logical column
    // block (cb ^ r) so the linear LDS write leaves data at the swizzled slot.
    const int sr = lane >> 3, scb = lane & 7;
    const int scol = ((scb ^ sr) << 3);               // element offset within 64-col tile
    const unsigned short* aptr[4];
    const unsigned short* bptr[5];
#pragma unroll
    for (int i = 0; i < 4; ++i)
        aptr[i] = xb + (size_t)(bm0 + (wid + i * 4) * 8 + sr) * FEAT + scol;
#pragma unroll
    for (int i = 0; i < 5; ++i)
        bptr[i] = epb + (size_t)(bn0 + (wid + i * 4) * 8 + sr) * FEAT + scol;

    // swizzled read offsets: addr = row*128 + ((CB ^ (row&7)) << 4), row&7 == lf&7
    int raA[4], raB[5];
#pragma unroll
    for (int f = 0; f < 4; ++f) raA[f] = (wm * 64 + f * 16 + lf) * 128;
#pragma unroll
    for (int f = 0; f < 5; ++f) raB[f] = 16384 + (wn * 80 + f * 16 + lf) * 128;
    const int sw = lf & 7;

    f32x4 acc[4][5] = {};

    for (int t = 0; t < 16; ++t) {
        __syncthreads();   // previous tile's reads done before overwrite
#pragma unroll
        for (int i = 0; i < 4; ++i)
            gload16(aptr[i], smem + (wid + i * 4) * 1024);
#pragma unroll
        for (int i = 0; i < 5; ++i)
            gload16(bptr[i], smem + 16384 + (wid + i * 4) * 1024);
#pragma unroll
        for (int i = 0; i < 4; ++i) aptr[i] += 64;
#pragma unroll
        for (int i = 0; i < 5; ++i) bptr[i] += 64;
        __syncthreads();   // drains vmcnt -> staged data visible to all waves
#pragma unroll
        for (int kk2 = 0; kk2 < 2; ++kk2) {
            const int off = (((kk2 * 4 + ls) ^ sw) << 4);
            short8 a[4], b[5];
#pragma unroll
            for (int f = 0; f < 4; ++f)
                a[f] = *(const short8*)(smem + raA[f] + off);
#pragma unroll
            for (int f = 0; f < 5; ++f)
                b[f] = *(const short8*)(smem + raB[f] + off);
#pragma unroll
            for (int fm = 0; fm < 4; ++fm)
#pragma unroll
                for (int fn = 0; fn < 5; ++fn)
                    acc[fm][fn] = __builtin_amdgcn_mfma_f32_16x16x32_bf16(a[fm], b[fn], acc[fm][fn], 0, 0, 0);
        }
    }

    // epilogue: d = sqrt(max(xsq - 2*dot + psq, 0)); min over groups of 10.
    // 4 passes (p = fm), dls[32][161] f32 = 20.6 KB fits the single buffer.
    float* dls = (float*)smem;
    const int tr = ls * 4, tc = lf;
    const int cls0 = bn0 / 10;  // = ntile * 16
#pragma unroll
    for (int p = 0; p < 4; ++p) {
        __syncthreads();
#pragma unroll
        for (int fn = 0; fn < 5; ++fn) {
            int col = wn * 80 + fn * 16 + tc;
            float pq = psq_s[col];
#pragma unroll
            for (int r = 0; r < 4; ++r) {
                float d2 = xsq_s[wm * 64 + p * 16 + tr + r] - 2.f * acc[p][fn][r] + pq;
                dls[(wm * 16 + tr + r) * 161 + col] = sqrtf(fmaxf(d2, 0.f));
            }
        }
        __syncthreads();
#pragma unroll
        for (int i = 0; i < 2; ++i) {
            int task = tid + i * 256;      // 512 tasks: 32 rows x 16 classes
            int rr = task >> 4, cl = task & 15;
            float m = 1e30f;
#pragma unroll
            for (int j = 0; j < 10; ++j) m = fminf(m, dls[rr * 161 + cl * 10 + j]);
            int grow = bm0 + (rr >> 4) * 64 + p * 16 + (rr & 15);
            int gcls = cls0 + cl;
            if (gcls < NCLS) out[(size_t)grow * NCLS + gcls] = m;
        }
    }
}

extern "C" void kernel_launch(void* const* d_in, const int* in_sizes, int n_in,
                              void* d_out, int out_size, void* d_ws, size_t ws_size,
                              hipStream_t stream) {
    const float* x      = (const float*)d_in[0];
    const float* protos = (const float*)d_in[1];
    const float* enc_w  = (const float*)d_in[2];
    const float* enc_b  = (const float*)d_in[3];
    float* out = (float*)d_out;
    char* ws = (char*)d_ws;

    unsigned short* xb  = (unsigned short*)ws;                   // 16384*1024*2 = 33554432
    unsigned short* epb = (unsigned short*)(ws + 33554432);      // 1120*1024*2  = 2293760
    unsigned short* prb = (unsigned short*)(ws + 35848192);      // 1024*1024*2  = 2097152
    unsigned short* wtb = (unsigned short*)(ws + 37945344);      // 1024*1024*2  = 2097152
    float* xsq = (float*)(ws + 40042496);                        // 16384*4
    float* psq = (float*)(ws + 40108032);                        // 1120*4

    // zero the padded ep rows (1000..1119) so staging reads defined data
    hipMemsetAsync(epb + (size_t)1000 * FEAT, 0, (size_t)120 * FEAT * 2, stream);

    k_prep_x<<<4096, 256, 0, stream>>>(x, xb, xsq);
    k_prep_protos<<<1024, 256, 0, stream>>>(protos, prb);
    k_transpose_w<<<dim3(32, 32), 256, 0, stream>>>(enc_w, wtb);
    k_enc_gemm<<<64, 256, 0, stream>>>(prb, wtb, enc_b, epb);
    k_psq<<<280, 256, 0, stream>>>(epb, psq);
    k_main<<<896, 256, 0, stream>>>(xb, epb, xsq, psq, out);
}

// Round 10
// 109.070 us; speedup vs baseline: 1.1509x; 1.0947x over previous
//
#include <hip/hip_runtime.h>
#include <hip/hip_bf16.h>
#include <stdint.h>

#define FEAT 1024
#define NALL 1000
#define NPAD 1120
#define NCLS 100

typedef __attribute__((ext_vector_type(8))) short short8;
typedef __attribute__((ext_vector_type(4))) float f32x4;
typedef __attribute__((ext_vector_type(4))) unsigned short us4;

__device__ __forceinline__ unsigned short f2bf(float f) {
    union { float f; uint32_t u; } v; v.f = f;
    uint32_t u = v.u;
    return (unsigned short)((u + 0x7FFFu + ((u >> 16) & 1u)) >> 16);
}

__device__ __forceinline__ void gload16(const void* g, void* l) {
    __builtin_amdgcn_global_load_lds((__attribute__((address_space(1))) void*)g,
                                     (__attribute__((address_space(3))) void*)l,
                                     16, 0, 0);
}

// K1: x (16384x1024 f32) -> bf16, plus row sum-of-squares
__global__ __launch_bounds__(256) void k_prep_x(const float* __restrict__ x,
                                                unsigned short* __restrict__ xb,
                                                float* __restrict__ xsq) {
    int row = blockIdx.x * 4 + (threadIdx.x >> 6);
    int lane = threadIdx.x & 63;
    const float4* xr = (const float4*)(x + (size_t)row * FEAT);
    float s = 0.f;
#pragma unroll
    for (int i = 0; i < 4; ++i) {
        float4 v = xr[lane + i * 64];
        s += v.x * v.x + v.y * v.y + v.z * v.z + v.w * v.w;
        us4 o;
        o[0] = f2bf(v.x); o[1] = f2bf(v.y); o[2] = f2bf(v.z); o[3] = f2bf(v.w);
        *(us4*)(xb + (size_t)row * FEAT + (size_t)(lane + i * 64) * 4) = o;
    }
#pragma unroll
    for (int off = 32; off; off >>= 1) s += __shfl_xor(s, off);
    if (lane == 0) xsq[row] = s;
}

// K2a: protos (1000x1024 f32) -> bf16 padded to 1024 rows (pad = 0)
__global__ __launch_bounds__(256) void k_prep_protos(const float* __restrict__ p,
                                                     unsigned short* __restrict__ pb) {
    int row = blockIdx.x;
    int t = threadIdx.x;
    us4 o;
    if (row < NALL) {
        float4 v = ((const float4*)(p + (size_t)row * FEAT))[t];
        o[0] = f2bf(v.x); o[1] = f2bf(v.y); o[2] = f2bf(v.z); o[3] = f2bf(v.w);
    } else {
        o[0] = 0; o[1] = 0; o[2] = 0; o[3] = 0;
    }
    *(us4*)(pb + (size_t)row * FEAT + (size_t)t * 4) = o;
}

// K2b: enc_w (1024x1024 f32) -> transposed bf16 (wt[n][k] = enc_w[k][n])
__global__ __launch_bounds__(256) void k_transpose_w(const float* __restrict__ w,
                                                     unsigned short* __restrict__ wt) {
    __shared__ float tile[32][33];
    int bx = blockIdx.x, by = blockIdx.y;
    int tx = threadIdx.x & 31, ty = threadIdx.x >> 5;
#pragma unroll
    for (int i = 0; i < 4; ++i) {
        int r = by * 32 + ty + i * 8;
        tile[ty + i * 8][tx] = w[(size_t)r * FEAT + bx * 32 + tx];
    }
    __syncthreads();
#pragma unroll
    for (int i = 0; i < 4; ++i) {
        int r = bx * 32 + ty + i * 8;
        wt[(size_t)r * FEAT + by * 32 + tx] = f2bf(tile[tx][ty + i * 8]);
    }
}

// K2c: encoder GEMM: ep = protos @ enc_w + b. Writes epb rows in class-major
// permuted order: n' = (n%100)*10 + n/100.
__global__ __launch_bounds__(256) void k_enc_gemm(const unsigned short* __restrict__ A,
                                                  const unsigned short* __restrict__ B,
                                                  const float* __restrict__ bias,
                                                  unsigned short* __restrict__ epb) {
    __shared__ __align__(16) char smem[32768];
    int bm0 = (blockIdx.x >> 3) * 128;
    int bn0 = (blockIdx.x & 7) * 128;
    int tid = threadIdx.x, lane = tid & 63, wid = tid >> 6;
    int wm = wid >> 1, wn = wid & 1;
    int ls = lane >> 4, lf = lane & 15;
    f32x4 acc[4][4] = {};
    for (int k0 = 0; k0 < FEAT; k0 += 64) {
        __syncthreads();
#pragma unroll
        for (int i = 0; i < 4; ++i) {
            int ci = wid + i * 4;
            int r = ci * 8 + (lane >> 3), c = (lane & 7) * 8;
            gload16(A + (size_t)(bm0 + r) * FEAT + k0 + c, smem + ci * 1024);
            gload16(B + (size_t)(bn0 + r) * FEAT + k0 + c, smem + 16384 + ci * 1024);
        }
        __syncthreads();
#pragma unroll
        for (int kk = 0; kk < 64; kk += 32) {
            short8 a[4], b[4];
#pragma unroll
            for (int f = 0; f < 4; ++f) {
                a[f] = *(const short8*)(smem + (wm * 64 + f * 16 + lf) * 128 + (kk + ls * 8) * 2);
                b[f] = *(const short8*)(smem + 16384 + (wn * 64 + f * 16 + lf) * 128 + (kk + ls * 8) * 2);
            }
#pragma unroll
            for (int fm = 0; fm < 4; ++fm)
#pragma unroll
                for (int fn = 0; fn < 4; ++fn)
                    acc[fm][fn] = __builtin_amdgcn_mfma_f32_16x16x32_bf16(a[fm], b[fn], acc[fm][fn], 0, 0, 0);
        }
    }
    int tr = ls * 4, tc = lf;
#pragma unroll
    for (int fn = 0; fn < 4; ++fn) {
        int col = bn0 + wn * 64 + fn * 16 + tc;
        float bb = bias[col];
#pragma unroll
        for (int fm = 0; fm < 4; ++fm) {
#pragma unroll
            for (int r = 0; r < 4; ++r) {
                int row = bm0 + wm * 64 + fm * 16 + tr + r;
                if (row < NALL) {
                    int pr = (row % 100) * 10 + row / 100;
                    epb[(size_t)pr * FEAT + col] = f2bf(acc[fm][fn][r] + bb);
                }
            }
        }
    }
}

// K2d: p_sq per (permuted) ep row; pad rows get 1e30
__global__ __launch_bounds__(256) void k_psq(const unsigned short* __restrict__ epb,
                                             float* __restrict__ psq) {
    int row = blockIdx.x * 4 + (threadIdx.x >> 6);
    int lane = threadIdx.x & 63;
    if (row >= NPAD) return;
    float s = 0.f;
    const short8* r8 = (const short8*)(epb + (size_t)row * FEAT);
#pragma unroll
    for (int i = 0; i < 2; ++i) {
        short8 v = r8[lane + i * 64];
#pragma unroll
        for (int j = 0; j < 8; ++j) {
            union { uint32_t u; float f; } c;
            c.u = ((uint32_t)(unsigned short)v[j]) << 16;
            s += c.f * c.f;
        }
    }
#pragma unroll
    for (int off = 32; off; off >>= 1) s += __shfl_xor(s, off);
    if (lane == 0) psq[row] = (row < NALL) ? s : 1e30f;
}

// K3: main GEMM (16384 x 1120 x 1024) + fused sqrt + min-over-10 epilogue.
// OCCUPANCY ROUND: BM=128, BN=80 (8 classes x 10 protos — min stays in-block),
// BK=64, 4 waves (4M x 1N), wave-tile 32x80, acc[2][5] = 40 regs (+28 frags).
// Total regs ~105 <= 128 granule -> 4 waves/SIMD -> 4 blocks/CU (16 waves/CU),
// LDS 27 KB. Same proven staging/read swizzle as r2/r9. Grid 128x14 = 1792.
__global__ __launch_bounds__(256, 4) void k_main(const unsigned short* __restrict__ xb,
                                                 const unsigned short* __restrict__ epb,
                                                 const float* __restrict__ xsq,
                                                 const float* __restrict__ psq,
                                                 float* __restrict__ out) {
    __shared__ __align__(16) char smem[27648];
    // A [128][64] @0 (16 KB), B [80][64] @16384 (10 KB), xsq_s @26624, psq_s @27136
    const int bid = blockIdx.x;                       // 1792 blocks
    const int swz = (bid & 7) * 224 + (bid >> 3);     // XCD-chunk swizzle (1792%8==0)
    const int bm0 = (swz / 14) * 128;
    const int nt  = swz % 14;
    const int bn0 = nt * 80;
    const int tid = threadIdx.x, lane = tid & 63, wid = tid >> 6;
    const int ls = lane >> 4, lf = lane & 15;
    float* xsq_s = (float*)(smem + 26624);
    float* psq_s = (float*)(smem + 27136);
    if (tid < 128) xsq_s[tid] = xsq[bm0 + tid];
    if (tid < 80)  psq_s[tid] = psq[bn0 + tid];

    // staging (rule 21): lane (r=lane>>3, cb=lane&7) loads logical col block
    // (cb ^ r) so the linear LDS write lands at the swizzled slot.
    const int sr = lane >> 3, scb = lane & 7;
    const int scol = ((scb ^ sr) << 3);
    const unsigned short* aptr[4];
    const unsigned short* bptr[3];
#pragma unroll
    for (int i = 0; i < 4; ++i)
        aptr[i] = xb + (size_t)(bm0 + (wid + i * 4) * 8 + sr) * FEAT + scol;
#pragma unroll
    for (int j = 0; j < 3; ++j) {
        int cj = wid + j * 4;
        bptr[j] = epb + (size_t)(bn0 + (cj < 10 ? cj : 0) * 8 + sr) * FEAT + scol;
    }

    // swizzled read offsets: addr = row*128 + ((CB ^ (row&7)) << 4)
    int raA[2], raB[5];
#pragma unroll
    for (int f = 0; f < 2; ++f) raA[f] = (wid * 32 + f * 16 + lf) * 128;
#pragma unroll
    for (int f = 0; f < 5; ++f) raB[f] = 16384 + (f * 16 + lf) * 128;
    const int sw = lf & 7;

    f32x4 acc[2][5] = {};

    for (int t = 0; t < 16; ++t) {
        __syncthreads();   // previous tile's reads done before overwrite
#pragma unroll
        for (int i = 0; i < 4; ++i)
            gload16(aptr[i], smem + (wid + i * 4) * 1024);
#pragma unroll
        for (int j = 0; j < 3; ++j) {
            int cj = wid + j * 4;
            if (cj < 10) gload16(bptr[j], smem + 16384 + cj * 1024);
        }
#pragma unroll
        for (int i = 0; i < 4; ++i) aptr[i] += 64;
#pragma unroll
        for (int j = 0; j < 3; ++j) bptr[j] += 64;
        __syncthreads();   // drains vmcnt -> staged data visible
#pragma unroll
        for (int kk2 = 0; kk2 < 2; ++kk2) {
            const int off = (((kk2 * 4 + ls) ^ sw) << 4);
            short8 a[2], b[5];
#pragma unroll
            for (int f = 0; f < 2; ++f)
                a[f] = *(const short8*)(smem + raA[f] + off);
#pragma unroll
            for (int f = 0; f < 5; ++f)
                b[f] = *(const short8*)(smem + raB[f] + off);
#pragma unroll
            for (int fm = 0; fm < 2; ++fm)
#pragma unroll
                for (int fn = 0; fn < 5; ++fn)
                    acc[fm][fn] = __builtin_amdgcn_mfma_f32_16x16x32_bf16(a[fm], b[fn], acc[fm][fn], 0, 0, 0);
        }
    }

    // epilogue: d = sqrt(max(xsq - 2*dot + psq, 0)); min over groups of 10.
    // 2 passes (p = fm): dls[64][81] f32 = 20.7 KB fits below xsq_s.
    float* dls = (float*)smem;
    const int tr = ls * 4;
#pragma unroll
    for (int p = 0; p < 2; ++p) {
        __syncthreads();
#pragma unroll
        for (int fn = 0; fn < 5; ++fn) {
            int col = fn * 16 + lf;
            float pq = psq_s[col];
#pragma unroll
            for (int r = 0; r < 4; ++r) {
                float d2 = xsq_s[wid * 32 + p * 16 + tr + r] - 2.f * acc[p][fn][r] + pq;
                dls[(wid * 16 + tr + r) * 81 + col] = sqrtf(fmaxf(d2, 0.f));
            }
        }
        __syncthreads();
#pragma unroll
        for (int i = 0; i < 2; ++i) {
            int task = tid + i * 256;      // 512 tasks: 64 rows x 8 classes
            int rr = task >> 3, cl = task & 7;
            float m = 1e30f;
#pragma unroll
            for (int j = 0; j < 10; ++j) m = fminf(m, dls[rr * 81 + cl * 10 + j]);
            int grow = bm0 + (rr >> 4) * 32 + p * 16 + (rr & 15);
            int gcls = nt * 8 + cl;
            if (gcls < NCLS) out[(size_t)grow * NCLS + gcls] = m;
        }
    }
}

extern "C" void kernel_launch(void* const* d_in, const int* in_sizes, int n_in,
                              void* d_out, int out_size, void* d_ws, size_t ws_size,
                              hipStream_t stream) {
    const float* x      = (const float*)d_in[0];
    const float* protos = (const float*)d_in[1];
    const float* enc_w  = (const float*)d_in[2];
    const float* enc_b  = (const float*)d_in[3];
    float* out = (float*)d_out;
    char* ws = (char*)d_ws;

    unsigned short* xb  = (unsigned short*)ws;                   // 16384*1024*2 = 33554432
    unsigned short* epb = (unsigned short*)(ws + 33554432);      // 1120*1024*2  = 2293760
    unsigned short* prb = (unsigned short*)(ws + 35848192);      // 1024*1024*2  = 2097152
    unsigned short* wtb = (unsigned short*)(ws + 37945344);      // 1024*1024*2  = 2097152
    float* xsq = (float*)(ws + 40042496);                        // 16384*4
    float* psq = (float*)(ws + 40108032);                        // 1120*4

    // zero the padded ep rows (1000..1119) so staging reads defined data
    hipMemsetAsync(epb + (size_t)1000 * FEAT, 0, (size_t)120 * FEAT * 2, stream);

    k_prep_x<<<4096, 256, 0, stream>>>(x, xb, xsq);
    k_prep_protos<<<1024, 256, 0, stream>>>(protos, prb);
    k_transpose_w<<<dim3(32, 32), 256, 0, stream>>>(enc_w, wtb);
    k_enc_gemm<<<64, 256, 0, stream>>>(prb, wtb, enc_b, epb);
    k_psq<<<280, 256, 0, stream>>>(epb, psq);
    k_main<<<1792, 256, 0, stream>>>(xb, epb, xsq, psq, out);
}